// Round 2
// baseline (633.526 us; speedup 1.0000x reference)
//
#include <hip/hip_runtime.h>

#define S_ 1024
#define H_ 12
#define DH_ 64
#define D_ 768
#define B_ 2
#define BH_ 24
#define QSZ_ (B_*H_*S_*DH_)   /* 1572864 */
#define OUTSZ_ (B_*S_*D_)     /* 1572864 */

// ---------------- K1: QKV projection GEMMs (z selects q/k/v) ----------------
__global__ __launch_bounds__(256) void proj_kernel(
    const float* __restrict__ q_in, const float* __restrict__ k_in, const float* __restrict__ v_in,
    const float* __restrict__ Wq, const float* __restrict__ bq,
    const float* __restrict__ Wk, const float* __restrict__ bk,
    const float* __restrict__ Wv, const float* __restrict__ bv,
    float* __restrict__ qw, float* __restrict__ kw, float* __restrict__ vw)
{
    const int z = blockIdx.z;
    const float* A    = z==0 ? q_in : (z==1 ? k_in : v_in);
    const float* W    = z==0 ? Wq   : (z==1 ? Wk   : Wv);
    const float* bias = z==0 ? bq   : (z==1 ? bk   : bv);
    float* outp       = z==0 ? qw   : (z==1 ? kw   : vw);

    __shared__ float As[16][68];   // As[kk][m] (transposed stage)
    __shared__ float Bs[16][68];   // Bs[kk][n]
    const int tid = threadIdx.x;
    const int ty = tid >> 4, tx = tid & 15;
    const int m0 = blockIdx.y * 64;
    const int n0 = blockIdx.x * 64;
    const int ia = tid >> 2, j4 = tid & 3;     // A-stage mapping
    const int kb = tid >> 4, n4 = tid & 15;    // B-stage mapping
    float acc[4][4] = {};
    for (int k0 = 0; k0 < D_; k0 += 16) {
        float4 a = *(const float4*)&A[(size_t)(m0+ia)*D_ + k0 + 4*j4];
        float4 w = *(const float4*)&W[(size_t)(k0+kb)*D_ + n0 + 4*n4];
        As[4*j4+0][ia]=a.x; As[4*j4+1][ia]=a.y; As[4*j4+2][ia]=a.z; As[4*j4+3][ia]=a.w;
        *(float4*)&Bs[kb][4*n4] = w;
        __syncthreads();
        #pragma unroll
        for (int kk = 0; kk < 16; ++kk) {
            float4 av  = *(const float4*)&As[kk][ty*4];
            float4 bv4 = *(const float4*)&Bs[kk][tx*4];
            float ar[4]={av.x,av.y,av.z,av.w}, br[4]={bv4.x,bv4.y,bv4.z,bv4.w};
            #pragma unroll
            for (int ii=0; ii<4; ++ii)
                #pragma unroll
                for (int jj=0; jj<4; ++jj)
                    acc[ii][jj] += ar[ii]*br[jj];
        }
        __syncthreads();
    }
    // n-tile width 64 == head size: head h = blockIdx.x
    const int h = blockIdx.x;
    float4 b4 = *(const float4*)&bias[n0 + tx*4];
    #pragma unroll
    for (int ii=0; ii<4; ++ii) {
        int r = m0 + ty*4 + ii;
        int bb = r >> 10, s = r & 1023;
        float4 v;
        v.x = acc[ii][0] + b4.x; v.y = acc[ii][1] + b4.y;
        v.z = acc[ii][2] + b4.z; v.w = acc[ii][3] + b4.w;
        *(float4*)&outp[(((size_t)bb*H_ + h)*S_ + s)*DH_ + tx*4] = v;
    }
}

// ---------------- K2a: scores = Q @ K^T per (b,h) ----------------
__global__ __launch_bounds__(256) void qk_kernel(
    const float* __restrict__ qw, const float* __restrict__ kw, float* __restrict__ sc)
{
    const int bh = blockIdx.z;
    const float* Q  = qw + (size_t)bh*S_*DH_;
    const float* Km = kw + (size_t)bh*S_*DH_;
    __shared__ float As[64][68];   // As[d][j]
    __shared__ float Bs[64][68];   // Bs[d][k]
    const int tid = threadIdx.x;
    const int ty = tid >> 4, tx = tid & 15;
    const int j0 = blockIdx.y * 64, k0 = blockIdx.x * 64;
    #pragma unroll
    for (int r = 0; r < 4; ++r) {
        int idx = tid + 256*r;
        int i = idx >> 4, c4 = idx & 15;
        float4 qv = *(const float4*)&Q [(size_t)(j0+i)*DH_ + 4*c4];
        float4 kv = *(const float4*)&Km[(size_t)(k0+i)*DH_ + 4*c4];
        As[4*c4+0][i]=qv.x; As[4*c4+1][i]=qv.y; As[4*c4+2][i]=qv.z; As[4*c4+3][i]=qv.w;
        Bs[4*c4+0][i]=kv.x; Bs[4*c4+1][i]=kv.y; Bs[4*c4+2][i]=kv.z; Bs[4*c4+3][i]=kv.w;
    }
    __syncthreads();
    float acc[4][4] = {};
    for (int d = 0; d < 64; ++d) {
        float4 av  = *(const float4*)&As[d][ty*4];
        float4 bv4 = *(const float4*)&Bs[d][tx*4];
        float ar[4]={av.x,av.y,av.z,av.w}, br[4]={bv4.x,bv4.y,bv4.z,bv4.w};
        #pragma unroll
        for (int ii=0; ii<4; ++ii)
            #pragma unroll
            for (int jj=0; jj<4; ++jj)
                acc[ii][jj] += ar[ii]*br[jj];
    }
    float* srow = sc + (size_t)bh*S_*S_;
    #pragma unroll
    for (int ii=0; ii<4; ++ii) {
        int j = j0 + ty*4 + ii;
        float4 v = {acc[ii][0],acc[ii][1],acc[ii][2],acc[ii][3]};
        *(float4*)&srow[(size_t)j*S_ + k0 + tx*4] = v;
    }
}

// ------- K2b: scores[bh,j,k] += sum_d q[bh,j,d]*pos[k,j,d]  (pos read once) -------
__global__ __launch_bounds__(256) void score_bias_kernel(
    const float* __restrict__ pos, const float* __restrict__ qw, float* __restrict__ sc)
{
    const int j = blockIdx.y;
    const int k = blockIdx.x*256 + threadIdx.x;
    __shared__ float qs[24][64];
    for (int idx = threadIdx.x; idx < 24*64; idx += 256) {
        int bh = idx >> 6, d = idx & 63;
        qs[bh][d] = qw[((size_t)bh*S_ + j)*DH_ + d];
    }
    __syncthreads();
    const float* prow = pos + ((size_t)k*S_ + j)*DH_;   // pos[k][j][:]
    float4 p[16];
    #pragma unroll
    for (int r=0; r<16; ++r) p[r] = ((const float4*)prow)[r];
    #pragma unroll
    for (int bh=0; bh<24; ++bh) {
        float s = 0.f;
        #pragma unroll
        for (int d4=0; d4<16; ++d4) {
            float4 q4 = *(const float4*)&qs[bh][4*d4];
            s += p[d4].x*q4.x + p[d4].y*q4.y + p[d4].z*q4.z + p[d4].w*q4.w;
        }
        sc[((size_t)bh*S_ + j)*S_ + k] += s;
    }
}

// ---------------- K3: softmax rows (scale + mask + stable softmax, in place) ----------------
__global__ __launch_bounds__(256) void softmax_kernel(
    float* __restrict__ sc, const float* __restrict__ mask)
{
    const int row = blockIdx.x;            // row = bh*S + j
    const int b = row / (H_*S_);
    float* srow = sc + (size_t)row*S_;
    const float* mrow = mask + (size_t)b*S_;
    const int tid = threadIdx.x;
    float4 x  = *(float4*)&srow[tid*4];
    float4 m4 = *(const float4*)&mrow[tid*4];
    x.x = x.x*0.125f + m4.x*(-1e9f);
    x.y = x.y*0.125f + m4.y*(-1e9f);
    x.z = x.z*0.125f + m4.z*(-1e9f);
    x.w = x.w*0.125f + m4.w*(-1e9f);
    float mx = fmaxf(fmaxf(x.x,x.y),fmaxf(x.z,x.w));
    #pragma unroll
    for (int off=32; off>0; off>>=1) mx = fmaxf(mx, __shfl_down(mx, off, 64));
    __shared__ float redm[4], reds[4];
    const int wid = tid>>6, lane = tid&63;
    if (lane==0) redm[wid]=mx;
    __syncthreads();
    mx = fmaxf(fmaxf(redm[0],redm[1]), fmaxf(redm[2],redm[3]));
    float4 e;
    e.x = __expf(x.x-mx); e.y = __expf(x.y-mx);
    e.z = __expf(x.z-mx); e.w = __expf(x.w-mx);
    float sm = e.x+e.y+e.z+e.w;
    #pragma unroll
    for (int off=32; off>0; off>>=1) sm += __shfl_down(sm, off, 64);
    if (lane==0) reds[wid]=sm;
    __syncthreads();
    float inv = 1.0f/(reds[0]+reds[1]+reds[2]+reds[3]);
    e.x*=inv; e.y*=inv; e.z*=inv; e.w*=inv;
    *(float4*)&srow[tid*4] = e;
}

// ---------------- K4a: ctx = W @ V per (b,h), written (b,s,h*64+d) ----------------
__global__ __launch_bounds__(256) void wv_kernel(
    const float* __restrict__ sc, const float* __restrict__ vw, float* __restrict__ ctx)
{
    const int bh = blockIdx.y;
    const float* Wm = sc + (size_t)bh*S_*S_;
    const float* V  = vw + (size_t)bh*S_*DH_;
    __shared__ float As[16][68];   // As[kk][j]
    __shared__ float Bs[16][68];   // Bs[kk][d]
    const int tid = threadIdx.x;
    const int ty = tid >> 4, tx = tid & 15;
    const int j0 = blockIdx.x * 64;
    const int ia = tid >> 2, j4 = tid & 3;
    const int kb = tid >> 4, n4 = tid & 15;
    float acc[4][4] = {};
    for (int k0 = 0; k0 < S_; k0 += 16) {
        float4 wv4 = *(const float4*)&Wm[(size_t)(j0+ia)*S_ + k0 + 4*j4];
        float4 vv  = *(const float4*)&V[(size_t)(k0+kb)*DH_ + 4*n4];
        As[4*j4+0][ia]=wv4.x; As[4*j4+1][ia]=wv4.y; As[4*j4+2][ia]=wv4.z; As[4*j4+3][ia]=wv4.w;
        *(float4*)&Bs[kb][4*n4] = vv;
        __syncthreads();
        #pragma unroll
        for (int kk=0; kk<16; ++kk) {
            float4 av  = *(const float4*)&As[kk][ty*4];
            float4 bv4 = *(const float4*)&Bs[kk][tx*4];
            float ar[4]={av.x,av.y,av.z,av.w}, br[4]={bv4.x,bv4.y,bv4.z,bv4.w};
            #pragma unroll
            for (int ii=0; ii<4; ++ii)
                #pragma unroll
                for (int jj=0; jj<4; ++jj)
                    acc[ii][jj] += ar[ii]*br[jj];
        }
        __syncthreads();
    }
    const int b = bh/12, h = bh%12;
    #pragma unroll
    for (int ii=0; ii<4; ++ii) {
        int s = j0 + ty*4 + ii;
        float4 v = {acc[ii][0],acc[ii][1],acc[ii][2],acc[ii][3]};
        *(float4*)&ctx[((size_t)b*S_ + s)*D_ + h*64 + tx*4] = v;
    }
}

// ------- K4b: ctx[bh,j,:] += sum_k w[bh,j,k]*pos[j,k,:]  (pos read once) -------
__global__ __launch_bounds__(256) void ctx_bias_kernel(
    const float* __restrict__ pos, const float* __restrict__ sc, float* __restrict__ ctx)
{
    const int j = blockIdx.x;
    const int tid = threadIdx.x;
    const int d = tid & 63, qt = tid >> 6;   // 4 wave-groups over k-quarters
    __shared__ float wch[24][256];           // weights chunk, 24 KB
    __shared__ float part[4][24][64];        // partials,      24 KB
    float acc[24] = {};
    const float* P2 = pos + (size_t)j*S_*DH_;  // pos[j][k][d]
    for (int kc = 0; kc < 4; ++kc) {
        __syncthreads();
        for (int idx = tid; idx < 24*256; idx += 256) {
            int bh = idx >> 8, kk = idx & 255;
            wch[bh][kk] = sc[((size_t)bh*S_ + j)*S_ + kc*256 + kk];
        }
        __syncthreads();
        const int kbase = qt*64;
        #pragma unroll 4
        for (int k4 = 0; k4 < 16; ++k4) {
            int kl = kbase + k4*4;
            float p0 = P2[(size_t)(kc*256 + kl+0)*DH_ + d];
            float p1 = P2[(size_t)(kc*256 + kl+1)*DH_ + d];
            float p2 = P2[(size_t)(kc*256 + kl+2)*DH_ + d];
            float p3 = P2[(size_t)(kc*256 + kl+3)*DH_ + d];
            #pragma unroll
            for (int bh = 0; bh < 24; ++bh) {
                float4 w4 = *(const float4*)&wch[bh][kl];
                acc[bh] += w4.x*p0 + w4.y*p1 + w4.z*p2 + w4.w*p3;
            }
        }
    }
    #pragma unroll
    for (int bh = 0; bh < 24; ++bh) part[qt][bh][d] = acc[bh];
    __syncthreads();
    for (int idx = tid; idx < 24*64; idx += 256) {
        int bh = idx >> 6, dd = idx & 63;
        float ssum = part[0][bh][dd] + part[1][bh][dd] + part[2][bh][dd] + part[3][bh][dd];
        int b = bh / 12, h = bh % 12;
        ctx[((size_t)b*S_ + j)*D_ + h*64 + dd] += ssum;
    }
}

// ---------------- K5: out = ctx @ Wo + bo ----------------
__global__ __launch_bounds__(256) void out_gemm_kernel(
    const float* __restrict__ A, const float* __restrict__ W, const float* __restrict__ bias,
    float* __restrict__ outp)
{
    __shared__ float As[16][68];
    __shared__ float Bs[16][68];
    const int tid = threadIdx.x;
    const int ty = tid >> 4, tx = tid & 15;
    const int m0 = blockIdx.y * 64;
    const int n0 = blockIdx.x * 64;
    const int ia = tid >> 2, j4 = tid & 3;
    const int kb = tid >> 4, n4 = tid & 15;
    float acc[4][4] = {};
    for (int k0 = 0; k0 < D_; k0 += 16) {
        float4 a = *(const float4*)&A[(size_t)(m0+ia)*D_ + k0 + 4*j4];
        float4 w = *(const float4*)&W[(size_t)(k0+kb)*D_ + n0 + 4*n4];
        As[4*j4+0][ia]=a.x; As[4*j4+1][ia]=a.y; As[4*j4+2][ia]=a.z; As[4*j4+3][ia]=a.w;
        *(float4*)&Bs[kb][4*n4] = w;
        __syncthreads();
        #pragma unroll
        for (int kk = 0; kk < 16; ++kk) {
            float4 av  = *(const float4*)&As[kk][ty*4];
            float4 bv4 = *(const float4*)&Bs[kk][tx*4];
            float ar[4]={av.x,av.y,av.z,av.w}, br[4]={bv4.x,bv4.y,bv4.z,bv4.w};
            #pragma unroll
            for (int ii=0; ii<4; ++ii)
                #pragma unroll
                for (int jj=0; jj<4; ++jj)
                    acc[ii][jj] += ar[ii]*br[jj];
        }
        __syncthreads();
    }
    float4 b4 = *(const float4*)&bias[n0 + tx*4];
    #pragma unroll
    for (int ii=0; ii<4; ++ii) {
        int r = m0 + ty*4 + ii;
        float4 v;
        v.x = acc[ii][0] + b4.x; v.y = acc[ii][1] + b4.y;
        v.z = acc[ii][2] + b4.z; v.w = acc[ii][3] + b4.w;
        *(float4*)&outp[(size_t)r*D_ + n0 + tx*4] = v;
    }
}

extern "C" void kernel_launch(void* const* d_in, const int* in_sizes, int n_in,
                              void* d_out, int out_size, void* d_ws, size_t ws_size,
                              hipStream_t stream) {
    const float* q_in = (const float*)d_in[0];
    const float* k_in = (const float*)d_in[1];
    const float* v_in = (const float*)d_in[2];
    const float* pos  = (const float*)d_in[3];
    const float* mask = (const float*)d_in[4];
    const float* Wq   = (const float*)d_in[5];
    const float* bq   = (const float*)d_in[6];
    const float* Wk   = (const float*)d_in[7];
    const float* bk   = (const float*)d_in[8];
    const float* Wv   = (const float*)d_in[9];
    const float* bv   = (const float*)d_in[10];
    const float* Wo   = (const float*)d_in[11];
    const float* bo   = (const float*)d_in[12];

    float* outp = (float*)d_out;               // (B,S,D)
    float* WEI  = outp + OUTSZ_;               // (B,H,S,S) — scores scratch then weights
    float* ws   = (float*)d_ws;
    float* QW  = ws;                           // (B,H,S,DH)
    float* KW  = ws + (size_t)QSZ_;
    float* VW  = ws + (size_t)2*QSZ_;
    float* CTX = ws + (size_t)3*QSZ_;          // (B,S,H*DH)

    proj_kernel      <<<dim3(12,32,3), 256, 0, stream>>>(q_in,k_in,v_in,Wq,bq,Wk,bk,Wv,bv,QW,KW,VW);
    qk_kernel        <<<dim3(16,16,24),256, 0, stream>>>(QW,KW,WEI);
    score_bias_kernel<<<dim3(4,1024),  256, 0, stream>>>(pos,QW,WEI);
    softmax_kernel   <<<dim3(24576),   256, 0, stream>>>(WEI,mask);
    wv_kernel        <<<dim3(16,24),   256, 0, stream>>>(WEI,VW,CTX);
    ctx_bias_kernel  <<<dim3(1024),    256, 0, stream>>>(pos,WEI,CTX);
    out_gemm_kernel  <<<dim3(12,32),   256, 0, stream>>>(CTX,Wo,bo,outp);
}

// Round 5
// 421.198 us; speedup vs baseline: 1.5041x; 1.5041x over previous
//
#include <hip/hip_runtime.h>

#define S_ 1024
#define H_ 12
#define DH_ 64
#define D_ 768
#define B_ 2
#define BH_ 24
#define OUTSZ_ (B_*S_*D_)

typedef short bf16x8 __attribute__((ext_vector_type(8)));
typedef float f32x4 __attribute__((ext_vector_type(4)));

#define MFMA16(a,b,c) __builtin_amdgcn_mfma_f32_16x16x32_bf16(a,b,c,0,0,0)

__device__ __forceinline__ short f2bf(float x){
  union { float f; unsigned u; } v; v.f = x;
  unsigned r = (v.u + 0x7FFFu + ((v.u>>16)&1u)) >> 16;
  return (short)r;
}

__device__ __forceinline__ uint4 pack8(float4 a, float4 b){
  uint4 r;
  r.x = ((unsigned)(unsigned short)f2bf(a.x)) | (((unsigned)(unsigned short)f2bf(a.y))<<16);
  r.y = ((unsigned)(unsigned short)f2bf(a.z)) | (((unsigned)(unsigned short)f2bf(a.w))<<16);
  r.z = ((unsigned)(unsigned short)f2bf(b.x)) | (((unsigned)(unsigned short)f2bf(b.y))<<16);
  r.w = ((unsigned)(unsigned short)f2bf(b.z)) | (((unsigned)(unsigned short)f2bf(b.w))<<16);
  return r;
}

// ---------- P0a: convert q_in/k_in/v_in fp32 -> bf16 (row-major [m][k]) ----------
__global__ __launch_bounds__(256) void cvt_in_kernel(
    const float* __restrict__ q, const float* __restrict__ k, const float* __restrict__ v,
    short* __restrict__ aq, short* __restrict__ ak, short* __restrict__ av)
{
    const float* src = blockIdx.y==0 ? q : (blockIdx.y==1 ? k : v);
    short* dst       = blockIdx.y==0 ? aq : (blockIdx.y==1 ? ak : av);
    size_t i = ((size_t)blockIdx.x*256 + threadIdx.x)*4;
    float4 x = *(const float4*)&src[i];
    short4 o; o.x=f2bf(x.x); o.y=f2bf(x.y); o.z=f2bf(x.z); o.w=f2bf(x.w);
    *(short4*)&dst[i] = o;
}

// ---------- P0b: transpose+convert W[k][n] fp32 -> WT[n][k] bf16 ----------
__global__ __launch_bounds__(256) void wt_kernel(
    const float* __restrict__ Wq, const float* __restrict__ Wk,
    const float* __restrict__ Wv, const float* __restrict__ Wo,
    short* __restrict__ Tq, short* __restrict__ Tk, short* __restrict__ Tv, short* __restrict__ To)
{
    const int z = blockIdx.z;
    const float* W = z==0?Wq:(z==1?Wk:(z==2?Wv:Wo));
    short* T       = z==0?Tq:(z==1?Tk:(z==2?Tv:To));
    __shared__ short tile[64][65];
    const int k0 = blockIdx.y*64, n0 = blockIdx.x*64;
    const int t = threadIdx.x;
    const int kr = t>>4, nc = (t&15)*4;
    #pragma unroll
    for (int p=0;p<4;p++){
        int k = p*16 + kr;
        float4 w = *(const float4*)&W[(size_t)(k0+k)*D_ + n0 + nc];
        tile[k][nc+0]=f2bf(w.x); tile[k][nc+1]=f2bf(w.y);
        tile[k][nc+2]=f2bf(w.z); tile[k][nc+3]=f2bf(w.w);
    }
    __syncthreads();
    #pragma unroll
    for (int p=0;p<4;p++){
        int n = p*16 + kr;
        short4 o; o.x=tile[nc+0][n]; o.y=tile[nc+1][n]; o.z=tile[nc+2][n]; o.w=tile[nc+3][n];
        *(short4*)&T[(size_t)(n0+n)*D_ + k0 + nc] = o;
    }
}

// ---------- K1: QKV projections via MFMA. QB/KB: [bh][s][d]; V -> VT [bh][d][s] ----------
__global__ __launch_bounds__(256) void proj_mfma_kernel(
    const short* __restrict__ aq, const short* __restrict__ ak, const short* __restrict__ av,
    const short* __restrict__ Tq, const short* __restrict__ Tk, const short* __restrict__ Tv,
    const float* __restrict__ bq, const float* __restrict__ bk, const float* __restrict__ bv,
    short* __restrict__ QB, short* __restrict__ KB, short* __restrict__ VTB)
{
    const int z = blockIdx.z;
    const short* A  = z==0?aq:(z==1?ak:av);
    const short* WT = z==0?Tq:(z==1?Tk:Tv);
    const float* bias = z==0?bq:(z==1?bk:bv);
    __shared__ short As[128][72];
    __shared__ short Bs[64][72];
    const int tid = threadIdx.x;
    const int w = tid>>6, lane = tid&63, g = lane>>4, r16 = lane&15;
    const int m0 = blockIdx.y*128, h = blockIdx.x, n0 = h*64;
    f32x4 acc[2][4] = {};
    for (int kc=0; kc<12; ++kc){
        {
            int row = tid>>1, half = tid&1;
            const uint4* src = (const uint4*)&A[(size_t)(m0+row)*D_ + kc*64 + half*32];
            uint4* dst = (uint4*)&As[row][half*32];
            dst[0]=src[0]; dst[1]=src[1]; dst[2]=src[2]; dst[3]=src[3];
        }
        if (tid < 128){
            int row = tid>>1, half = tid&1;
            const uint4* src = (const uint4*)&WT[(size_t)(n0+row)*D_ + kc*64 + half*32];
            uint4* dst = (uint4*)&Bs[row][half*32];
            dst[0]=src[0]; dst[1]=src[1]; dst[2]=src[2]; dst[3]=src[3];
        }
        __syncthreads();
        #pragma unroll
        for (int ks=0; ks<2; ++ks){
            bf16x8 a0 = *(const bf16x8*)&As[w*32      + r16][ks*32 + g*8];
            bf16x8 a1 = *(const bf16x8*)&As[w*32 + 16 + r16][ks*32 + g*8];
            #pragma unroll
            for (int ni=0; ni<4; ++ni){
                bf16x8 b = *(const bf16x8*)&Bs[ni*16 + r16][ks*32 + g*8];
                acc[0][ni] = MFMA16(a0, b, acc[0][ni]);
                acc[1][ni] = MFMA16(a1, b, acc[1][ni]);
            }
        }
        __syncthreads();
    }
    #pragma unroll
    for (int mi=0; mi<2; ++mi)
    #pragma unroll
    for (int ni=0; ni<4; ++ni)
    #pragma unroll
    for (int r=0; r<4; ++r){
        int m = m0 + w*32 + mi*16 + g*4 + r;
        int b = m>>10, s = m&1023;
        int d = ni*16 + r16;
        short o = f2bf(acc[mi][ni][r] + bias[n0 + d]);
        if (z==2) VTB[(((size_t)b*H_ + h)*DH_ + d)*S_ + s] = o;
        else {
            short* dst = (z==0) ? QB : KB;
            dst[(((size_t)b*H_ + h)*S_ + s)*DH_ + d] = o;
        }
    }
}

// ---------- K2a: raw scores = Q @ K^T per bh (MFMA) ----------
__global__ __launch_bounds__(256) void qk_mfma_kernel(
    const short* __restrict__ QB, const short* __restrict__ KB, float* __restrict__ sc)
{
    const int bh = blockIdx.z;
    const short* Q = QB + (size_t)bh*S_*DH_;
    const short* K = KB + (size_t)bh*S_*DH_;
    __shared__ short Qs[128][72];
    __shared__ short Ks[128][72];
    const int tid = threadIdx.x;
    const int w = tid>>6, lane = tid&63, g = lane>>4, r16 = lane&15;
    const int j0 = blockIdx.y*128, k0 = blockIdx.x*128;
    {
        int row = tid>>1, half = tid&1;
        const uint4* sq = (const uint4*)&Q[(size_t)(j0+row)*DH_ + half*32];
        uint4* dq = (uint4*)&Qs[row][half*32];
        dq[0]=sq[0]; dq[1]=sq[1]; dq[2]=sq[2]; dq[3]=sq[3];
        const uint4* sk = (const uint4*)&K[(size_t)(k0+row)*DH_ + half*32];
        uint4* dk = (uint4*)&Ks[row][half*32];
        dk[0]=sk[0]; dk[1]=sk[1]; dk[2]=sk[2]; dk[3]=sk[3];
    }
    __syncthreads();
    f32x4 acc[2][8] = {};
    #pragma unroll
    for (int ks=0; ks<2; ++ks){
        bf16x8 a0 = *(const bf16x8*)&Qs[w*32      + r16][ks*32 + g*8];
        bf16x8 a1 = *(const bf16x8*)&Qs[w*32 + 16 + r16][ks*32 + g*8];
        #pragma unroll
        for (int ni=0; ni<8; ++ni){
            bf16x8 b = *(const bf16x8*)&Ks[ni*16 + r16][ks*32 + g*8];
            acc[0][ni] = MFMA16(a0, b, acc[0][ni]);
            acc[1][ni] = MFMA16(a1, b, acc[1][ni]);
        }
    }
    float* srow = sc + (size_t)bh*S_*S_;
    #pragma unroll
    for (int mi=0; mi<2; ++mi)
    #pragma unroll
    for (int ni=0; ni<8; ++ni)
    #pragma unroll
    for (int r=0; r<4; ++r){
        int j = j0 + w*32 + mi*16 + g*4 + r;
        int k = k0 + ni*16 + r16;
        srow[(size_t)j*S_ + k] = acc[mi][ni][r];
    }
}

// ---------- K2b: scores[bh,j,k] += q[bh,j,:].pos[k,j,:]  (MFMA, pos coalesced, read once) ----------
__global__ __launch_bounds__(256) void sbias_mfma_kernel(
    const float* __restrict__ pos, const short* __restrict__ QB, float* __restrict__ sc)
{
    const int j0 = blockIdx.y*4, k0 = blockIdx.x*64;
    __shared__ short Qs[4][32][72];
    __shared__ short Ps[4][64][72];
    const int tid = threadIdx.x;
    const int w = tid>>6, lane = tid&63, g = lane>>4, r16 = lane&15;
    if (tid < 128){
        int jj = tid&3, bhp = tid>>2;
        uint4* dst = (uint4*)&Qs[jj][bhp][0];
        if (bhp < BH_){
            const uint4* src = (const uint4*)&QB[((size_t)bhp*S_ + j0+jj)*DH_];
            #pragma unroll
            for (int i=0;i<8;i++) dst[i]=src[i];
        } else {
            uint4 z4 = {0,0,0,0};
            #pragma unroll
            for (int i=0;i<8;i++) dst[i]=z4;
        }
    }
    {
        int k = tid>>2, jj = tid&3;
        const float* src = &pos[((size_t)(k0+k)*S_ + j0+jj)*DH_];
        uint4* dst = (uint4*)&Ps[jj][k][0];
        #pragma unroll
        for (int i=0;i<8;i++){
            float4 x0 = *(const float4*)&src[i*8];
            float4 x1 = *(const float4*)&src[i*8+4];
            dst[i] = pack8(x0,x1);
        }
    }
    __syncthreads();
    f32x4 acc[2][4] = {};
    #pragma unroll
    for (int ks=0; ks<2; ++ks){
        bf16x8 a0 = *(const bf16x8*)&Qs[w][r16][ks*32 + g*8];
        bf16x8 a1 = *(const bf16x8*)&Qs[w][16 + r16][ks*32 + g*8];
        #pragma unroll
        for (int ni=0; ni<4; ++ni){
            bf16x8 b = *(const bf16x8*)&Ps[w][ni*16 + r16][ks*32 + g*8];
            acc[0][ni] = MFMA16(a0, b, acc[0][ni]);
            acc[1][ni] = MFMA16(a1, b, acc[1][ni]);
        }
    }
    #pragma unroll
    for (int mi=0; mi<2; ++mi)
    #pragma unroll
    for (int r=0; r<4; ++r){
        int bh = mi*16 + g*4 + r;
        if (bh < BH_){
            float* row = sc + ((size_t)bh*S_ + (j0+w))*S_ + k0;
            #pragma unroll
            for (int ni=0; ni<4; ++ni)
                row[ni*16 + r16] += acc[mi][ni][r];
        }
    }
}

// ---------- K3: softmax rows (scale + mask + stable softmax, in place) ----------
__global__ __launch_bounds__(256) void softmax_kernel(
    float* __restrict__ sc, const float* __restrict__ mask)
{
    const int row = blockIdx.x;            // row = bh*S + j
    const int b = row / (H_*S_);
    float* srow = sc + (size_t)row*S_;
    const float* mrow = mask + (size_t)b*S_;
    const int tid = threadIdx.x;
    float4 x  = *(float4*)&srow[tid*4];
    float4 m4 = *(const float4*)&mrow[tid*4];
    x.x = x.x*0.125f + m4.x*(-1e9f);
    x.y = x.y*0.125f + m4.y*(-1e9f);
    x.z = x.z*0.125f + m4.z*(-1e9f);
    x.w = x.w*0.125f + m4.w*(-1e9f);
    float mx = fmaxf(fmaxf(x.x,x.y),fmaxf(x.z,x.w));
    #pragma unroll
    for (int off=32; off>0; off>>=1) mx = fmaxf(mx, __shfl_down(mx, off, 64));
    __shared__ float redm[4], reds[4];
    const int wid = tid>>6, lane = tid&63;
    if (lane==0) redm[wid]=mx;
    __syncthreads();
    mx = fmaxf(fmaxf(redm[0],redm[1]), fmaxf(redm[2],redm[3]));
    float4 e;
    e.x = __expf(x.x-mx); e.y = __expf(x.y-mx);
    e.z = __expf(x.z-mx); e.w = __expf(x.w-mx);
    float sm = e.x+e.y+e.z+e.w;
    #pragma unroll
    for (int off=32; off>0; off>>=1) sm += __shfl_down(sm, off, 64);
    if (lane==0) reds[wid]=sm;
    __syncthreads();
    float inv = 1.0f/(reds[0]+reds[1]+reds[2]+reds[3]);
    e.x*=inv; e.y*=inv; e.z*=inv; e.w*=inv;
    *(float4*)&srow[tid*4] = e;
}

// ---------- K4a: ctx = W @ V per bh via MFMA (B from VT rows), ctx f32 (b,s,h*64+d) ----------
__global__ __launch_bounds__(256) void wv_mfma_kernel(
    const float* __restrict__ sc, const short* __restrict__ VTB, float* __restrict__ CTX)
{
    const int bh = blockIdx.y, m0 = blockIdx.x*64;
    const float* W  = sc  + (size_t)bh*S_*S_;
    const short* VT = VTB + (size_t)bh*DH_*S_;
    __shared__ short Ws[64][72];
    __shared__ short Vs[64][72];
    const int tid = threadIdx.x;
    const int w = tid>>6, lane = tid&63, g = lane>>4, r16 = lane&15;
    f32x4 acc[4] = {};
    for (int kc=0; kc<16; ++kc){
        if (tid < 128){
            int row = tid>>1, half = tid&1;      // row 0..63
            const float* src = &W[(size_t)(m0+row)*S_ + kc*64 + half*32];
            uint4* dst = (uint4*)&Ws[row][half*32];
            #pragma unroll
            for (int i=0;i<4;i++){
                float4 x0 = *(const float4*)&src[i*8];
                float4 x1 = *(const float4*)&src[i*8+4];
                dst[i] = pack8(x0,x1);
            }
        } else {
            int t2 = tid-128;
            int row = t2>>1, half = t2&1;        // row 0..63
            const uint4* src = (const uint4*)&VT[(size_t)row*S_ + kc*64 + half*32];
            uint4* dst = (uint4*)&Vs[row][half*32];
            dst[0]=src[0]; dst[1]=src[1]; dst[2]=src[2]; dst[3]=src[3];
        }
        __syncthreads();
        #pragma unroll
        for (int ks=0; ks<2; ++ks){
            bf16x8 a = *(const bf16x8*)&Ws[w*16 + r16][ks*32 + g*8];
            #pragma unroll
            for (int ni=0; ni<4; ++ni){
                bf16x8 b = *(const bf16x8*)&Vs[ni*16 + r16][ks*32 + g*8];
                acc[ni] = MFMA16(a, b, acc[ni]);
            }
        }
        __syncthreads();
    }
    const int b = bh/H_, h = bh%H_;
    #pragma unroll
    for (int ni=0; ni<4; ++ni)
    #pragma unroll
    for (int r=0; r<4; ++r){
        int j = m0 + w*16 + g*4 + r;
        int d = ni*16 + r16;
        CTX[((size_t)b*S_ + j)*D_ + h*DH_ + d] = acc[ni][r];
    }
}

// ---------- K4b: ctxb = ctx + sum_k w[bh,j,k]*pos[j,k,:]  -> bf16 (pos read once) ----------
__global__ __launch_bounds__(256) void ctx_bias_kernel(
    const float* __restrict__ pos, const float* __restrict__ sc,
    const float* __restrict__ CTX, short* __restrict__ CTXB)
{
    const int j = blockIdx.x;
    const int tid = threadIdx.x;
    const int d = tid & 63, qt = tid >> 6;
    __shared__ float wch[24][256];
    __shared__ float part[4][24][64];
    float acc[24] = {};
    const float* P2 = pos + (size_t)j*S_*DH_;
    for (int kc = 0; kc < 4; ++kc) {
        __syncthreads();
        for (int idx = tid; idx < 24*256; idx += 256) {
            int bh = idx >> 8, kk = idx & 255;
            wch[bh][kk] = sc[((size_t)bh*S_ + j)*S_ + kc*256 + kk];
        }
        __syncthreads();
        const int kbase = qt*64;
        #pragma unroll 4
        for (int k4 = 0; k4 < 16; ++k4) {
            int kl = kbase + k4*4;
            float p0 = P2[(size_t)(kc*256 + kl+0)*DH_ + d];
            float p1 = P2[(size_t)(kc*256 + kl+1)*DH_ + d];
            float p2 = P2[(size_t)(kc*256 + kl+2)*DH_ + d];
            float p3 = P2[(size_t)(kc*256 + kl+3)*DH_ + d];
            #pragma unroll
            for (int bh = 0; bh < 24; ++bh) {
                float4 w4 = *(const float4*)&wch[bh][kl];
                acc[bh] += w4.x*p0 + w4.y*p1 + w4.z*p2 + w4.w*p3;
            }
        }
    }
    #pragma unroll
    for (int bh = 0; bh < 24; ++bh) part[qt][bh][d] = acc[bh];
    __syncthreads();
    for (int idx = tid; idx < 24*64; idx += 256) {
        int bh = idx >> 6, dd = idx & 63;
        float ssum = part[0][bh][dd] + part[1][bh][dd] + part[2][bh][dd] + part[3][bh][dd];
        int b = bh / H_, h = bh % H_;
        size_t o = ((size_t)b*S_ + j)*D_ + h*DH_ + dd;
        CTXB[o] = f2bf(CTX[o] + ssum);
    }
}

// ---------- K5: out = ctxb @ Wo + bo (MFMA) ----------
__global__ __launch_bounds__(256) void out_mfma_kernel(
    const short* __restrict__ CTXB, const short* __restrict__ To,
    const float* __restrict__ bo, float* __restrict__ outp)
{
    const int m0 = blockIdx.y*64, n0 = blockIdx.x*64;
    __shared__ short As[64][72];
    __shared__ short Bs[64][72];
    const int tid = threadIdx.x;
    const int w = tid>>6, lane = tid&63, g = lane>>4, r16 = lane&15;
    f32x4 acc[4] = {};
    for (int kc=0; kc<12; ++kc){
        if (tid < 128){
            int row = tid>>1, half = tid&1;
            const uint4* src = (const uint4*)&CTXB[(size_t)(m0+row)*D_ + kc*64 + half*32];
            uint4* dst = (uint4*)&As[row][half*32];
            dst[0]=src[0]; dst[1]=src[1]; dst[2]=src[2]; dst[3]=src[3];
        } else {
            int t2 = tid-128;
            int row = t2>>1, half = t2&1;
            const uint4* src = (const uint4*)&To[(size_t)(n0+row)*D_ + kc*64 + half*32];
            uint4* dst = (uint4*)&Bs[row][half*32];
            dst[0]=src[0]; dst[1]=src[1]; dst[2]=src[2]; dst[3]=src[3];
        }
        __syncthreads();
        #pragma unroll
        for (int ks=0; ks<2; ++ks){
            bf16x8 a = *(const bf16x8*)&As[w*16 + r16][ks*32 + g*8];
            #pragma unroll
            for (int ni=0; ni<4; ++ni){
                bf16x8 b = *(const bf16x8*)&Bs[ni*16 + r16][ks*32 + g*8];
                acc[ni] = MFMA16(a, b, acc[ni]);
            }
        }
        __syncthreads();
    }
    #pragma unroll
    for (int ni=0; ni<4; ++ni)
    #pragma unroll
    for (int r=0; r<4; ++r){
        int m = m0 + w*16 + g*4 + r;
        int n = n0 + ni*16 + r16;
        outp[(size_t)m*D_ + n] = acc[ni][r] + bo[n];
    }
}

extern "C" void kernel_launch(void* const* d_in, const int* in_sizes, int n_in,
                              void* d_out, int out_size, void* d_ws, size_t ws_size,
                              hipStream_t stream) {
    const float* q_in = (const float*)d_in[0];
    const float* k_in = (const float*)d_in[1];
    const float* v_in = (const float*)d_in[2];
    const float* pos  = (const float*)d_in[3];
    const float* mask = (const float*)d_in[4];
    const float* Wq   = (const float*)d_in[5];
    const float* bq   = (const float*)d_in[6];
    const float* Wk   = (const float*)d_in[7];
    const float* bk   = (const float*)d_in[8];
    const float* Wv   = (const float*)d_in[9];
    const float* bv   = (const float*)d_in[10];
    const float* Wo   = (const float*)d_in[11];
    const float* bo   = (const float*)d_in[12];

    float* outp = (float*)d_out;               // (B,S,D)
    float* WEI  = outp + OUTSZ_;               // (B,H,S,S) raw scores -> weights

    char* w8 = (char*)d_ws;
    short* QB  = (short*)w8;                                   // 3,145,728 B
    short* KB  = (short*)(w8 + 1*3145728);
    short* VTB = (short*)(w8 + 2*3145728);
    short* WTq = (short*)(w8 + 3*3145728);                     // 4 x 1,179,648 B
    short* WTk = WTq + 768*768;
    short* WTv = WTk + 768*768;
    short* WTo = WTv + 768*768;
    char*  r2  = w8 + 3*3145728 + 4*1179648;                   // 14,155,776
    short* AQ  = (short*)r2;                                   // 3 x 3,145,728 B (pre-proj)
    short* AK  = AQ + (size_t)2048*768;
    short* AV  = AK + (size_t)2048*768;
    float* CTX  = (float*)r2;                                  // 6,291,456 B (post-proj reuse)
    short* CTXB = (short*)(r2 + 6291456);                      // 3,145,728 B

    cvt_in_kernel   <<<dim3(1536,3),   256, 0, stream>>>(q_in,k_in,v_in,AQ,AK,AV);
    wt_kernel       <<<dim3(12,12,4),  256, 0, stream>>>(Wq,Wk,Wv,Wo,WTq,WTk,WTv,WTo);
    proj_mfma_kernel<<<dim3(12,16,3),  256, 0, stream>>>(AQ,AK,AV,WTq,WTk,WTv,bq,bk,bv,QB,KB,VTB);
    qk_mfma_kernel  <<<dim3(8,8,24),   256, 0, stream>>>(QB,KB,WEI);
    sbias_mfma_kernel<<<dim3(16,256),  256, 0, stream>>>(pos,QB,WEI);
    softmax_kernel  <<<dim3(24576),    256, 0, stream>>>(WEI,mask);
    wv_mfma_kernel  <<<dim3(16,24),    256, 0, stream>>>(WEI,VTB,CTX);
    ctx_bias_kernel <<<dim3(1024),     256, 0, stream>>>(pos,WEI,CTX,CTXB);
    out_mfma_kernel <<<dim3(12,32),    256, 0, stream>>>(CTXB,WTo,bo,outp);
}

// Round 6
// 324.387 us; speedup vs baseline: 1.9530x; 1.2984x over previous
//
#include <hip/hip_runtime.h>

#define S_ 1024
#define H_ 12
#define DH_ 64
#define D_ 768
#define B_ 2
#define BH_ 24
#define OUTSZ_ (B_*S_*D_)

typedef short bf16x8 __attribute__((ext_vector_type(8)));
typedef float f32x4 __attribute__((ext_vector_type(4)));

#define MFMA16(a,b,c) __builtin_amdgcn_mfma_f32_16x16x32_bf16(a,b,c,0,0,0)

__device__ __forceinline__ short f2bf(float x){
  union { float f; unsigned u; } v; v.f = x;
  unsigned r = (v.u + 0x7FFFu + ((v.u>>16)&1u)) >> 16;
  return (short)r;
}

__device__ __forceinline__ uint4 pack8(float4 a, float4 b){
  uint4 r;
  r.x = ((unsigned)(unsigned short)f2bf(a.x)) | (((unsigned)(unsigned short)f2bf(a.y))<<16);
  r.y = ((unsigned)(unsigned short)f2bf(a.z)) | (((unsigned)(unsigned short)f2bf(a.w))<<16);
  r.z = ((unsigned)(unsigned short)f2bf(b.x)) | (((unsigned)(unsigned short)f2bf(b.y))<<16);
  r.w = ((unsigned)(unsigned short)f2bf(b.z)) | (((unsigned)(unsigned short)f2bf(b.w))<<16);
  return r;
}

// ---------- P0a: convert q_in/k_in/v_in fp32 -> bf16 (row-major [m][k]) ----------
__global__ __launch_bounds__(256) void cvt_in_kernel(
    const float* __restrict__ q, const float* __restrict__ k, const float* __restrict__ v,
    short* __restrict__ aq, short* __restrict__ ak, short* __restrict__ av)
{
    const float* src = blockIdx.y==0 ? q : (blockIdx.y==1 ? k : v);
    short* dst       = blockIdx.y==0 ? aq : (blockIdx.y==1 ? ak : av);
    size_t i = ((size_t)blockIdx.x*256 + threadIdx.x)*4;
    float4 x = *(const float4*)&src[i];
    short4 o; o.x=f2bf(x.x); o.y=f2bf(x.y); o.z=f2bf(x.z); o.w=f2bf(x.w);
    *(short4*)&dst[i] = o;
}

// ---------- P0b: transpose+convert W[k][n] fp32 -> WT[n][k] bf16 ----------
__global__ __launch_bounds__(256) void wt_kernel(
    const float* __restrict__ Wq, const float* __restrict__ Wk,
    const float* __restrict__ Wv, const float* __restrict__ Wo,
    short* __restrict__ Tq, short* __restrict__ Tk, short* __restrict__ Tv, short* __restrict__ To)
{
    const int z = blockIdx.z;
    const float* W = z==0?Wq:(z==1?Wk:(z==2?Wv:Wo));
    short* T       = z==0?Tq:(z==1?Tk:(z==2?Tv:To));
    __shared__ short tile[64][65];
    const int k0 = blockIdx.y*64, n0 = blockIdx.x*64;
    const int t = threadIdx.x;
    const int kr = t>>4, nc = (t&15)*4;
    #pragma unroll
    for (int p=0;p<4;p++){
        int k = p*16 + kr;
        float4 w = *(const float4*)&W[(size_t)(k0+k)*D_ + n0 + nc];
        tile[k][nc+0]=f2bf(w.x); tile[k][nc+1]=f2bf(w.y);
        tile[k][nc+2]=f2bf(w.z); tile[k][nc+3]=f2bf(w.w);
    }
    __syncthreads();
    #pragma unroll
    for (int p=0;p<4;p++){
        int n = p*16 + kr;
        short4 o; o.x=tile[nc+0][n]; o.y=tile[nc+1][n]; o.z=tile[nc+2][n]; o.w=tile[nc+3][n];
        *(short4*)&T[(size_t)(n0+n)*D_ + k0 + nc] = o;
    }
}

// ---------- K1: QKV projections via MFMA. QB/KB: [bh][s][d]; V -> VT [bh][d][s] ----------
__global__ __launch_bounds__(256) void proj_mfma_kernel(
    const short* __restrict__ aq, const short* __restrict__ ak, const short* __restrict__ av,
    const short* __restrict__ Tq, const short* __restrict__ Tk, const short* __restrict__ Tv,
    const float* __restrict__ bq, const float* __restrict__ bk, const float* __restrict__ bv,
    short* __restrict__ QB, short* __restrict__ KB, short* __restrict__ VTB)
{
    const int z = blockIdx.z;
    const short* A  = z==0?aq:(z==1?ak:av);
    const short* WT = z==0?Tq:(z==1?Tk:Tv);
    const float* bias = z==0?bq:(z==1?bk:bv);
    __shared__ short As[128][72];
    __shared__ short Bs[64][72];
    const int tid = threadIdx.x;
    const int w = tid>>6, lane = tid&63, g = lane>>4, r16 = lane&15;
    const int m0 = blockIdx.y*128, h = blockIdx.x, n0 = h*64;
    f32x4 acc[2][4] = {};
    for (int kc=0; kc<12; ++kc){
        {
            int row = tid>>1, half = tid&1;
            const uint4* src = (const uint4*)&A[(size_t)(m0+row)*D_ + kc*64 + half*32];
            uint4* dst = (uint4*)&As[row][half*32];
            dst[0]=src[0]; dst[1]=src[1]; dst[2]=src[2]; dst[3]=src[3];
        }
        if (tid < 128){
            int row = tid>>1, half = tid&1;
            const uint4* src = (const uint4*)&WT[(size_t)(n0+row)*D_ + kc*64 + half*32];
            uint4* dst = (uint4*)&Bs[row][half*32];
            dst[0]=src[0]; dst[1]=src[1]; dst[2]=src[2]; dst[3]=src[3];
        }
        __syncthreads();
        #pragma unroll
        for (int ks=0; ks<2; ++ks){
            bf16x8 a0 = *(const bf16x8*)&As[w*32      + r16][ks*32 + g*8];
            bf16x8 a1 = *(const bf16x8*)&As[w*32 + 16 + r16][ks*32 + g*8];
            #pragma unroll
            for (int ni=0; ni<4; ++ni){
                bf16x8 b = *(const bf16x8*)&Bs[ni*16 + r16][ks*32 + g*8];
                acc[0][ni] = MFMA16(a0, b, acc[0][ni]);
                acc[1][ni] = MFMA16(a1, b, acc[1][ni]);
            }
        }
        __syncthreads();
    }
    #pragma unroll
    for (int mi=0; mi<2; ++mi)
    #pragma unroll
    for (int ni=0; ni<4; ++ni)
    #pragma unroll
    for (int r=0; r<4; ++r){
        int m = m0 + w*32 + mi*16 + g*4 + r;
        int b = m>>10, s = m&1023;
        int d = ni*16 + r16;
        short o = f2bf(acc[mi][ni][r] + bias[n0 + d]);
        if (z==2) VTB[(((size_t)b*H_ + h)*DH_ + d)*S_ + s] = o;
        else {
            short* dst = (z==0) ? QB : KB;
            dst[(((size_t)b*H_ + h)*S_ + s)*DH_ + d] = o;
        }
    }
}

// ---------- K2a: raw scores = Q @ K^T per bh (MFMA) ----------
__global__ __launch_bounds__(256) void qk_mfma_kernel(
    const short* __restrict__ QB, const short* __restrict__ KB, float* __restrict__ sc)
{
    const int bh = blockIdx.z;
    const short* Q = QB + (size_t)bh*S_*DH_;
    const short* K = KB + (size_t)bh*S_*DH_;
    __shared__ short Qs[128][72];
    __shared__ short Ks[128][72];
    const int tid = threadIdx.x;
    const int w = tid>>6, lane = tid&63, g = lane>>4, r16 = lane&15;
    const int j0 = blockIdx.y*128, k0 = blockIdx.x*128;
    {
        int row = tid>>1, half = tid&1;
        const uint4* sq = (const uint4*)&Q[(size_t)(j0+row)*DH_ + half*32];
        uint4* dq = (uint4*)&Qs[row][half*32];
        dq[0]=sq[0]; dq[1]=sq[1]; dq[2]=sq[2]; dq[3]=sq[3];
        const uint4* sk = (const uint4*)&K[(size_t)(k0+row)*DH_ + half*32];
        uint4* dk = (uint4*)&Ks[row][half*32];
        dk[0]=sk[0]; dk[1]=sk[1]; dk[2]=sk[2]; dk[3]=sk[3];
    }
    __syncthreads();
    f32x4 acc[2][8] = {};
    #pragma unroll
    for (int ks=0; ks<2; ++ks){
        bf16x8 a0 = *(const bf16x8*)&Qs[w*32      + r16][ks*32 + g*8];
        bf16x8 a1 = *(const bf16x8*)&Qs[w*32 + 16 + r16][ks*32 + g*8];
        #pragma unroll
        for (int ni=0; ni<8; ++ni){
            bf16x8 b = *(const bf16x8*)&Ks[ni*16 + r16][ks*32 + g*8];
            acc[0][ni] = MFMA16(a0, b, acc[0][ni]);
            acc[1][ni] = MFMA16(a1, b, acc[1][ni]);
        }
    }
    float* srow = sc + (size_t)bh*S_*S_;
    #pragma unroll
    for (int mi=0; mi<2; ++mi)
    #pragma unroll
    for (int ni=0; ni<8; ++ni)
    #pragma unroll
    for (int r=0; r<4; ++r){
        int j = j0 + w*32 + mi*16 + g*4 + r;
        int k = k0 + ni*16 + r16;
        srow[(size_t)j*S_ + k] = acc[mi][ni][r];
    }
}

// ---------- K2b: scores[bh,j,k] += q[bh,j,:].pos[k,j,:]  (MFMA, pos coalesced, read once) ----------
__global__ __launch_bounds__(256) void sbias_mfma_kernel(
    const float* __restrict__ pos, const short* __restrict__ QB, float* __restrict__ sc)
{
    const int j0 = blockIdx.y*4, k0 = blockIdx.x*64;
    __shared__ short Qs[4][32][72];
    __shared__ short Ps[4][64][72];
    const int tid = threadIdx.x;
    const int w = tid>>6, lane = tid&63, g = lane>>4, r16 = lane&15;
    if (tid < 128){
        int jj = tid&3, bhp = tid>>2;
        uint4* dst = (uint4*)&Qs[jj][bhp][0];
        if (bhp < BH_){
            const uint4* src = (const uint4*)&QB[((size_t)bhp*S_ + j0+jj)*DH_];
            #pragma unroll
            for (int i=0;i<8;i++) dst[i]=src[i];
        } else {
            uint4 z4 = {0,0,0,0};
            #pragma unroll
            for (int i=0;i<8;i++) dst[i]=z4;
        }
    }
    {
        int k = tid>>2, jj = tid&3;
        const float* src = &pos[((size_t)(k0+k)*S_ + j0+jj)*DH_];
        uint4* dst = (uint4*)&Ps[jj][k][0];
        #pragma unroll
        for (int i=0;i<8;i++){
            float4 x0 = *(const float4*)&src[i*8];
            float4 x1 = *(const float4*)&src[i*8+4];
            dst[i] = pack8(x0,x1);
        }
    }
    __syncthreads();
    f32x4 acc[2][4] = {};
    #pragma unroll
    for (int ks=0; ks<2; ++ks){
        bf16x8 a0 = *(const bf16x8*)&Qs[w][r16][ks*32 + g*8];
        bf16x8 a1 = *(const bf16x8*)&Qs[w][16 + r16][ks*32 + g*8];
        #pragma unroll
        for (int ni=0; ni<4; ++ni){
            bf16x8 b = *(const bf16x8*)&Ps[w][ni*16 + r16][ks*32 + g*8];
            acc[0][ni] = MFMA16(a0, b, acc[0][ni]);
            acc[1][ni] = MFMA16(a1, b, acc[1][ni]);
        }
    }
    #pragma unroll
    for (int mi=0; mi<2; ++mi)
    #pragma unroll
    for (int r=0; r<4; ++r){
        int bh = mi*16 + g*4 + r;
        if (bh < BH_){
            float* row = sc + ((size_t)bh*S_ + (j0+w))*S_ + k0;
            #pragma unroll
            for (int ni=0; ni<4; ++ni)
                row[ni*16 + r16] += acc[mi][ni][r];
        }
    }
}

// ---------- K3: softmax rows (scale + mask + stable softmax, in place) ----------
__global__ __launch_bounds__(256) void softmax_kernel(
    float* __restrict__ sc, const float* __restrict__ mask)
{
    const int row = blockIdx.x;            // row = bh*S + j
    const int b = row / (H_*S_);
    float* srow = sc + (size_t)row*S_;
    const float* mrow = mask + (size_t)b*S_;
    const int tid = threadIdx.x;
    float4 x  = *(float4*)&srow[tid*4];
    float4 m4 = *(const float4*)&mrow[tid*4];
    x.x = x.x*0.125f + m4.x*(-1e9f);
    x.y = x.y*0.125f + m4.y*(-1e9f);
    x.z = x.z*0.125f + m4.z*(-1e9f);
    x.w = x.w*0.125f + m4.w*(-1e9f);
    float mx = fmaxf(fmaxf(x.x,x.y),fmaxf(x.z,x.w));
    #pragma unroll
    for (int off=32; off>0; off>>=1) mx = fmaxf(mx, __shfl_down(mx, off, 64));
    __shared__ float redm[4], reds[4];
    const int wid = tid>>6, lane = tid&63;
    if (lane==0) redm[wid]=mx;
    __syncthreads();
    mx = fmaxf(fmaxf(redm[0],redm[1]), fmaxf(redm[2],redm[3]));
    float4 e;
    e.x = __expf(x.x-mx); e.y = __expf(x.y-mx);
    e.z = __expf(x.z-mx); e.w = __expf(x.w-mx);
    float sm = e.x+e.y+e.z+e.w;
    #pragma unroll
    for (int off=32; off>0; off>>=1) sm += __shfl_down(sm, off, 64);
    if (lane==0) reds[wid]=sm;
    __syncthreads();
    float inv = 1.0f/(reds[0]+reds[1]+reds[2]+reds[3]);
    e.x*=inv; e.y*=inv; e.z*=inv; e.w*=inv;
    *(float4*)&srow[tid*4] = e;
}

// ---------- K4a: ctx = W @ V per bh via MFMA (B from VT rows), ctx f32 (b,s,h*64+d) ----------
__global__ __launch_bounds__(256) void wv_mfma_kernel(
    const float* __restrict__ sc, const short* __restrict__ VTB, float* __restrict__ CTX)
{
    const int bh = blockIdx.y, m0 = blockIdx.x*64;
    const float* W  = sc  + (size_t)bh*S_*S_;
    const short* VT = VTB + (size_t)bh*DH_*S_;
    __shared__ short Ws[64][72];
    __shared__ short Vs[64][72];
    const int tid = threadIdx.x;
    const int w = tid>>6, lane = tid&63, g = lane>>4, r16 = lane&15;
    f32x4 acc[4] = {};
    for (int kc=0; kc<16; ++kc){
        if (tid < 128){
            int row = tid>>1, half = tid&1;      // row 0..63
            const float* src = &W[(size_t)(m0+row)*S_ + kc*64 + half*32];
            uint4* dst = (uint4*)&Ws[row][half*32];
            #pragma unroll
            for (int i=0;i<4;i++){
                float4 x0 = *(const float4*)&src[i*8];
                float4 x1 = *(const float4*)&src[i*8+4];
                dst[i] = pack8(x0,x1);
            }
        } else {
            int t2 = tid-128;
            int row = t2>>1, half = t2&1;        // row 0..63
            const uint4* src = (const uint4*)&VT[(size_t)row*S_ + kc*64 + half*32];
            uint4* dst = (uint4*)&Vs[row][half*32];
            dst[0]=src[0]; dst[1]=src[1]; dst[2]=src[2]; dst[3]=src[3];
        }
        __syncthreads();
        #pragma unroll
        for (int ks=0; ks<2; ++ks){
            bf16x8 a = *(const bf16x8*)&Ws[w*16 + r16][ks*32 + g*8];
            #pragma unroll
            for (int ni=0; ni<4; ++ni){
                bf16x8 b = *(const bf16x8*)&Vs[ni*16 + r16][ks*32 + g*8];
                acc[ni] = MFMA16(a, b, acc[ni]);
            }
        }
        __syncthreads();
    }
    const int b = bh/H_, h = bh%H_;
    #pragma unroll
    for (int ni=0; ni<4; ++ni)
    #pragma unroll
    for (int r=0; r<4; ++r){
        int j = m0 + w*16 + g*4 + r;
        int d = ni*16 + r16;
        CTX[((size_t)b*S_ + j)*D_ + h*DH_ + d] = acc[ni][r];
    }
}

// ---------- K4b: ctxb = ctx + sum_k w[bh,j,k]*pos[j,k,:] -> bf16 (MFMA, dbuf prefetch) ----------
// Per j: D[bh][d] = sum_k W[bh][k]*posj[k][d].  A=W[bh][k] (k-contig), B=posj^T[d][k] (k-contig,
// built by transpose-on-LDS-write during fp32->bf16 conversion).
__global__ __launch_bounds__(256) void ctx_bias_mfma_kernel(
    const float* __restrict__ pos, const float* __restrict__ sc,
    const float* __restrict__ CTX, short* __restrict__ CTXB)
{
    const int j = blockIdx.x;
    const int tid = threadIdx.x;
    const int w = tid>>6, lane = tid&63, g = lane>>4, r16 = lane&15;
    __shared__ short Pt[2][64][72];   // [d][k] bf16 (transposed pos chunk)
    __shared__ short Ws[2][32][72];   // [bh][k] bf16 (weight rows, 24 used)

    // zero the pad rows 24..31 of both W buffers once
    for (int idx = tid; idx < 2*8*72; idx += 256){
        int buf = idx / (8*72), rem = idx - buf*(8*72);
        Ws[buf][24 + rem/72][rem - (rem/72)*72] = 0;
    }

    const float* Pj = pos + (size_t)j*S_*DH_;
    const int d4 = tid & 15;          // d-group (4 floats)
    const int kl = tid >> 4;          // k within 16-row group
    const int wrow0 = tid >> 4;       // W row 0..15
    const int wf4   = tid & 15;       // W float4 index

    float4 p[4]; float4 wr0, wr1;
    // ---- load chunk 0 into regs ----
    #pragma unroll
    for (int i=0;i<4;i++)
        p[i] = *(const float4*)&Pj[(size_t)(i*16 + kl)*DH_ + d4*4];
    wr0 = *(const float4*)&sc[((size_t)wrow0*S_ + j)*S_ + wf4*4];
    if (tid < 128)
        wr1 = *(const float4*)&sc[((size_t)(16+wrow0)*S_ + j)*S_ + wf4*4];
    // ---- store chunk 0 to LDS buf 0 ----
    #pragma unroll
    for (int i=0;i<4;i++){
        int k = i*16 + kl;
        Pt[0][d4*4+0][k] = f2bf(p[i].x);
        Pt[0][d4*4+1][k] = f2bf(p[i].y);
        Pt[0][d4*4+2][k] = f2bf(p[i].z);
        Pt[0][d4*4+3][k] = f2bf(p[i].w);
    }
    {
        short4 o; o.x=f2bf(wr0.x); o.y=f2bf(wr0.y); o.z=f2bf(wr0.z); o.w=f2bf(wr0.w);
        *(short4*)&Ws[0][wrow0][wf4*4] = o;
        if (tid < 128){
            short4 o1; o1.x=f2bf(wr1.x); o1.y=f2bf(wr1.y); o1.z=f2bf(wr1.z); o1.w=f2bf(wr1.w);
            *(short4*)&Ws[0][16+wrow0][wf4*4] = o1;
        }
    }
    __syncthreads();

    f32x4 acc[2] = {};
    for (int c=0; c<16; ++c){
        const int b = c & 1;
        if (c < 15){
            const int k0 = (c+1)*64;
            #pragma unroll
            for (int i=0;i<4;i++)
                p[i] = *(const float4*)&Pj[(size_t)(k0 + i*16 + kl)*DH_ + d4*4];
            wr0 = *(const float4*)&sc[((size_t)wrow0*S_ + j)*S_ + k0 + wf4*4];
            if (tid < 128)
                wr1 = *(const float4*)&sc[((size_t)(16+wrow0)*S_ + j)*S_ + k0 + wf4*4];
        }
        // compute on buf b: wave w owns n-tile w (d = w*16+r16)
        #pragma unroll
        for (int ks=0; ks<2; ++ks){
            bf16x8 bfr = *(const bf16x8*)&Pt[b][w*16 + r16][ks*32 + g*8];
            #pragma unroll
            for (int mi=0; mi<2; ++mi){
                bf16x8 afr = *(const bf16x8*)&Ws[b][mi*16 + r16][ks*32 + g*8];
                acc[mi] = MFMA16(afr, bfr, acc[mi]);
            }
        }
        __syncthreads();
        if (c < 15){
            const int nb = b ^ 1;
            #pragma unroll
            for (int i=0;i<4;i++){
                int k = i*16 + kl;
                Pt[nb][d4*4+0][k] = f2bf(p[i].x);
                Pt[nb][d4*4+1][k] = f2bf(p[i].y);
                Pt[nb][d4*4+2][k] = f2bf(p[i].z);
                Pt[nb][d4*4+3][k] = f2bf(p[i].w);
            }
            short4 o; o.x=f2bf(wr0.x); o.y=f2bf(wr0.y); o.z=f2bf(wr0.z); o.w=f2bf(wr0.w);
            *(short4*)&Ws[nb][wrow0][wf4*4] = o;
            if (tid < 128){
                short4 o1; o1.x=f2bf(wr1.x); o1.y=f2bf(wr1.y); o1.z=f2bf(wr1.z); o1.w=f2bf(wr1.w);
                *(short4*)&Ws[nb][16+wrow0][wf4*4] = o1;
            }
            __syncthreads();
        }
    }

    // epilogue: D row = bh (col=lane&15 -> d, row=(lane>>4)*4+reg -> bh)
    #pragma unroll
    for (int mi=0; mi<2; ++mi)
    #pragma unroll
    for (int r=0; r<4; ++r){
        int bh = mi*16 + g*4 + r;
        if (bh < BH_){
            int d = w*16 + r16;
            size_t o = ((size_t)(bh/H_)*S_ + j)*D_ + (bh%H_)*DH_ + d;
            CTXB[o] = f2bf(CTX[o] + acc[mi][r]);
        }
    }
}

// ---------- K5: out = ctxb @ Wo + bo (MFMA) ----------
__global__ __launch_bounds__(256) void out_mfma_kernel(
    const short* __restrict__ CTXB, const short* __restrict__ To,
    const float* __restrict__ bo, float* __restrict__ outp)
{
    const int m0 = blockIdx.y*64, n0 = blockIdx.x*64;
    __shared__ short As[64][72];
    __shared__ short Bs[64][72];
    const int tid = threadIdx.x;
    const int w = tid>>6, lane = tid&63, g = lane>>4, r16 = lane&15;
    f32x4 acc[4] = {};
    for (int kc=0; kc<12; ++kc){
        if (tid < 128){
            int row = tid>>1, half = tid&1;
            const uint4* src = (const uint4*)&CTXB[(size_t)(m0+row)*D_ + kc*64 + half*32];
            uint4* dst = (uint4*)&As[row][half*32];
            dst[0]=src[0]; dst[1]=src[1]; dst[2]=src[2]; dst[3]=src[3];
        } else {
            int t2 = tid-128;
            int row = t2>>1, half = t2&1;
            const uint4* src = (const uint4*)&To[(size_t)(n0+row)*D_ + kc*64 + half*32];
            uint4* dst = (uint4*)&Bs[row][half*32];
            dst[0]=src[0]; dst[1]=src[1]; dst[2]=src[2]; dst[3]=src[3];
        }
        __syncthreads();
        #pragma unroll
        for (int ks=0; ks<2; ++ks){
            bf16x8 a = *(const bf16x8*)&As[w*16 + r16][ks*32 + g*8];
            #pragma unroll
            for (int ni=0; ni<4; ++ni){
                bf16x8 b = *(const bf16x8*)&Bs[ni*16 + r16][ks*32 + g*8];
                acc[ni] = MFMA16(a, b, acc[ni]);
            }
        }
        __syncthreads();
    }
    #pragma unroll
    for (int ni=0; ni<4; ++ni)
    #pragma unroll
    for (int r=0; r<4; ++r){
        int m = m0 + w*16 + g*4 + r;
        int n = n0 + ni*16 + r16;
        outp[(size_t)m*D_ + n] = acc[ni][r] + bo[n];
    }
}

extern "C" void kernel_launch(void* const* d_in, const int* in_sizes, int n_in,
                              void* d_out, int out_size, void* d_ws, size_t ws_size,
                              hipStream_t stream) {
    const float* q_in = (const float*)d_in[0];
    const float* k_in = (const float*)d_in[1];
    const float* v_in = (const float*)d_in[2];
    const float* pos  = (const float*)d_in[3];
    const float* mask = (const float*)d_in[4];
    const float* Wq   = (const float*)d_in[5];
    const float* bq   = (const float*)d_in[6];
    const float* Wk   = (const float*)d_in[7];
    const float* bk   = (const float*)d_in[8];
    const float* Wv   = (const float*)d_in[9];
    const float* bv   = (const float*)d_in[10];
    const float* Wo   = (const float*)d_in[11];
    const float* bo   = (const float*)d_in[12];

    float* outp = (float*)d_out;               // (B,S,D)
    float* WEI  = outp + OUTSZ_;               // (B,H,S,S) raw scores -> weights

    char* w8 = (char*)d_ws;
    short* QB  = (short*)w8;                                   // 3,145,728 B
    short* KB  = (short*)(w8 + 1*3145728);
    short* VTB = (short*)(w8 + 2*3145728);
    short* WTq = (short*)(w8 + 3*3145728);                     // 4 x 1,179,648 B
    short* WTk = WTq + 768*768;
    short* WTv = WTk + 768*768;
    short* WTo = WTv + 768*768;
    char*  r2  = w8 + 3*3145728 + 4*1179648;                   // 14,155,776
    short* AQ  = (short*)r2;                                   // 3 x 3,145,728 B (pre-proj)
    short* AK  = AQ + (size_t)2048*768;
    short* AV  = AK + (size_t)2048*768;
    float* CTX  = (float*)r2;                                  // 6,291,456 B (post-proj reuse)
    short* CTXB = (short*)(r2 + 6291456);                      // 3,145,728 B

    cvt_in_kernel   <<<dim3(1536,3),   256, 0, stream>>>(q_in,k_in,v_in,AQ,AK,AV);
    wt_kernel       <<<dim3(12,12,4),  256, 0, stream>>>(Wq,Wk,Wv,Wo,WTq,WTk,WTv,WTo);
    proj_mfma_kernel<<<dim3(12,16,3),  256, 0, stream>>>(AQ,AK,AV,WTq,WTk,WTv,bq,bk,bv,QB,KB,VTB);
    qk_mfma_kernel  <<<dim3(8,8,24),   256, 0, stream>>>(QB,KB,WEI);
    sbias_mfma_kernel<<<dim3(16,256),  256, 0, stream>>>(pos,QB,WEI);
    softmax_kernel  <<<dim3(24576),    256, 0, stream>>>(WEI,mask);
    wv_mfma_kernel  <<<dim3(16,24),    256, 0, stream>>>(WEI,VTB,CTX);
    ctx_bias_mfma_kernel<<<dim3(1024), 256, 0, stream>>>(pos,WEI,CTX,CTXB);
    out_mfma_kernel <<<dim3(12,32),    256, 0, stream>>>(CTXB,WTo,bo,outp);
}

// Round 8
// 250.665 us; speedup vs baseline: 2.5274x; 1.2941x over previous
//
#include <hip/hip_runtime.h>

#define S_ 1024
#define H_ 12
#define DH_ 64
#define D_ 768
#define B_ 2
#define BH_ 24
#define OUTSZ_ (B_*S_*D_)

typedef short bf16x8 __attribute__((ext_vector_type(8)));
typedef float f32x4 __attribute__((ext_vector_type(4)));

#define MFMA16(a,b,c) __builtin_amdgcn_mfma_f32_16x16x32_bf16(a,b,c,0,0,0)

__device__ __forceinline__ short f2bf(float x){
  union { float f; unsigned u; } v; v.f = x;
  unsigned r = (v.u + 0x7FFFu + ((v.u>>16)&1u)) >> 16;
  return (short)r;
}
__device__ __forceinline__ float bf2f(short s){
  union { unsigned u; float f; } v; v.u = ((unsigned)(unsigned short)s) << 16;
  return v.f;
}

__device__ __forceinline__ uint4 pack8(float4 a, float4 b){
  uint4 r;
  r.x = ((unsigned)(unsigned short)f2bf(a.x)) | (((unsigned)(unsigned short)f2bf(a.y))<<16);
  r.y = ((unsigned)(unsigned short)f2bf(a.z)) | (((unsigned)(unsigned short)f2bf(a.w))<<16);
  r.z = ((unsigned)(unsigned short)f2bf(b.x)) | (((unsigned)(unsigned short)f2bf(b.y))<<16);
  r.w = ((unsigned)(unsigned short)f2bf(b.z)) | (((unsigned)(unsigned short)f2bf(b.w))<<16);
  return r;
}

// ---------- P0a: convert q_in/k_in/v_in fp32 -> bf16 ----------
__global__ __launch_bounds__(256) void cvt_in_kernel(
    const float* __restrict__ q, const float* __restrict__ k, const float* __restrict__ v,
    short* __restrict__ aq, short* __restrict__ ak, short* __restrict__ av)
{
    const float* src = blockIdx.y==0 ? q : (blockIdx.y==1 ? k : v);
    short* dst       = blockIdx.y==0 ? aq : (blockIdx.y==1 ? ak : av);
    size_t i = ((size_t)blockIdx.x*256 + threadIdx.x)*4;
    float4 x = *(const float4*)&src[i];
    short4 o; o.x=f2bf(x.x); o.y=f2bf(x.y); o.z=f2bf(x.z); o.w=f2bf(x.w);
    *(short4*)&dst[i] = o;
}

// ---------- P0b: transpose+convert W[k][n] fp32 -> WT[n][k] bf16 ----------
__global__ __launch_bounds__(256) void wt_kernel(
    const float* __restrict__ Wq, const float* __restrict__ Wk,
    const float* __restrict__ Wv, const float* __restrict__ Wo,
    short* __restrict__ Tq, short* __restrict__ Tk, short* __restrict__ Tv, short* __restrict__ To)
{
    const int z = blockIdx.z;
    const float* W = z==0?Wq:(z==1?Wk:(z==2?Wv:Wo));
    short* T       = z==0?Tq:(z==1?Tk:(z==2?Tv:To));
    __shared__ short tile[64][65];
    const int k0 = blockIdx.y*64, n0 = blockIdx.x*64;
    const int t = threadIdx.x;
    const int kr = t>>4, nc = (t&15)*4;
    #pragma unroll
    for (int p=0;p<4;p++){
        int k = p*16 + kr;
        float4 w = *(const float4*)&W[(size_t)(k0+k)*D_ + n0 + nc];
        tile[k][nc+0]=f2bf(w.x); tile[k][nc+1]=f2bf(w.y);
        tile[k][nc+2]=f2bf(w.z); tile[k][nc+3]=f2bf(w.w);
    }
    __syncthreads();
    #pragma unroll
    for (int p=0;p<4;p++){
        int n = p*16 + kr;
        short4 o; o.x=tile[nc+0][n]; o.y=tile[nc+1][n]; o.z=tile[nc+2][n]; o.w=tile[nc+3][n];
        *(short4*)&T[(size_t)(n0+n)*D_ + k0 + nc] = o;
    }
}

// ---------- K1: QKV projections via MFMA. QB/KB: [bh][s][d]; V -> VT [bh][d][s] ----------
__global__ __launch_bounds__(256) void proj_mfma_kernel(
    const short* __restrict__ aq, const short* __restrict__ ak, const short* __restrict__ av,
    const short* __restrict__ Tq, const short* __restrict__ Tk, const short* __restrict__ Tv,
    const float* __restrict__ bq, const float* __restrict__ bk, const float* __restrict__ bv,
    short* __restrict__ QB, short* __restrict__ KB, short* __restrict__ VTB)
{
    const int z = blockIdx.z;
    const short* A  = z==0?aq:(z==1?ak:av);
    const short* WT = z==0?Tq:(z==1?Tk:Tv);
    const float* bias = z==0?bq:(z==1?bk:bv);
    __shared__ short As[128][72];
    __shared__ short Bs[64][72];
    const int tid = threadIdx.x;
    const int w = tid>>6, lane = tid&63, g = lane>>4, r16 = lane&15;
    const int m0 = blockIdx.y*128, h = blockIdx.x, n0 = h*64;
    f32x4 acc[2][4] = {};
    for (int kc=0; kc<12; ++kc){
        {
            int row = tid>>1, half = tid&1;
            const uint4* src = (const uint4*)&A[(size_t)(m0+row)*D_ + kc*64 + half*32];
            uint4* dst = (uint4*)&As[row][half*32];
            dst[0]=src[0]; dst[1]=src[1]; dst[2]=src[2]; dst[3]=src[3];
        }
        if (tid < 128){
            int row = tid>>1, half = tid&1;
            const uint4* src = (const uint4*)&WT[(size_t)(n0+row)*D_ + kc*64 + half*32];
            uint4* dst = (uint4*)&Bs[row][half*32];
            dst[0]=src[0]; dst[1]=src[1]; dst[2]=src[2]; dst[3]=src[3];
        }
        __syncthreads();
        #pragma unroll
        for (int ks=0; ks<2; ++ks){
            bf16x8 a0 = *(const bf16x8*)&As[w*32      + r16][ks*32 + g*8];
            bf16x8 a1 = *(const bf16x8*)&As[w*32 + 16 + r16][ks*32 + g*8];
            #pragma unroll
            for (int ni=0; ni<4; ++ni){
                bf16x8 b = *(const bf16x8*)&Bs[ni*16 + r16][ks*32 + g*8];
                acc[0][ni] = MFMA16(a0, b, acc[0][ni]);
                acc[1][ni] = MFMA16(a1, b, acc[1][ni]);
            }
        }
        __syncthreads();
    }
    #pragma unroll
    for (int mi=0; mi<2; ++mi)
    #pragma unroll
    for (int ni=0; ni<4; ++ni)
    #pragma unroll
    for (int r=0; r<4; ++r){
        int m = m0 + w*32 + mi*16 + g*4 + r;
        int b = m>>10, s = m&1023;
        int d = ni*16 + r16;
        short o = f2bf(acc[mi][ni][r] + bias[n0 + d]);
        if (z==2) VTB[(((size_t)b*H_ + h)*DH_ + d)*S_ + s] = o;
        else {
            short* dst = (z==0) ? QB : KB;
            dst[(((size_t)b*H_ + h)*S_ + s)*DH_ + d] = o;
        }
    }
}

// ---------- K2: raw scores = Q @ K^T per bh (MFMA) -> WEI fp32 ----------
__global__ __launch_bounds__(256) void qk_mfma_kernel(
    const short* __restrict__ QB, const short* __restrict__ KB, float* __restrict__ sc)
{
    const int bh = blockIdx.z;
    const short* Q = QB + (size_t)bh*S_*DH_;
    const short* K = KB + (size_t)bh*S_*DH_;
    __shared__ short Qs[128][72];
    __shared__ short Ks[128][72];
    const int tid = threadIdx.x;
    const int w = tid>>6, lane = tid&63, g = lane>>4, r16 = lane&15;
    const int j0 = blockIdx.y*128, k0 = blockIdx.x*128;
    {
        int row = tid>>1, half = tid&1;
        const uint4* sq = (const uint4*)&Q[(size_t)(j0+row)*DH_ + half*32];
        uint4* dq = (uint4*)&Qs[row][half*32];
        dq[0]=sq[0]; dq[1]=sq[1]; dq[2]=sq[2]; dq[3]=sq[3];
        const uint4* sk = (const uint4*)&K[(size_t)(k0+row)*DH_ + half*32];
        uint4* dk = (uint4*)&Ks[row][half*32];
        dk[0]=sk[0]; dk[1]=sk[1]; dk[2]=sk[2]; dk[3]=sk[3];
    }
    __syncthreads();
    f32x4 acc[2][8] = {};
    #pragma unroll
    for (int ks=0; ks<2; ++ks){
        bf16x8 a0 = *(const bf16x8*)&Qs[w*32      + r16][ks*32 + g*8];
        bf16x8 a1 = *(const bf16x8*)&Qs[w*32 + 16 + r16][ks*32 + g*8];
        #pragma unroll
        for (int ni=0; ni<8; ++ni){
            bf16x8 b = *(const bf16x8*)&Ks[ni*16 + r16][ks*32 + g*8];
            acc[0][ni] = MFMA16(a0, b, acc[0][ni]);
            acc[1][ni] = MFMA16(a1, b, acc[1][ni]);
        }
    }
    float* srow = sc + (size_t)bh*S_*S_;
    #pragma unroll
    for (int mi=0; mi<2; ++mi)
    #pragma unroll
    for (int ni=0; ni<8; ++ni)
    #pragma unroll
    for (int r=0; r<4; ++r){
        int j = j0 + w*32 + mi*16 + g*4 + r;
        int k = k0 + ni*16 + r16;
        srow[(size_t)j*S_ + k] = acc[mi][ni][r];
    }
}

// ---------- K3: fused per-j  bias(einsum1) + softmax + pos-ctx(einsum2) ----------
__global__ __launch_bounds__(512) void fused_j_kernel(
    const float* __restrict__ pos, const short* __restrict__ QB,
    const float* __restrict__ mask, float* __restrict__ WEI, short* __restrict__ PBIAS)
{
    const int j = blockIdx.x;
    const int tid = threadIdx.x;
    const int w = tid>>6, lane = tid&63, g = lane>>4, r16 = lane&15;
    const int mi = w>>2, ni = w&3;
    __shared__ short SB[24][1032];     // scores/weights bf16
    __shared__ short Pt[2][64][72];    // pos chunk staging (dbuf)
    __shared__ short Qs[32][72];       // Q rows, zero-padded to 32

    // --- Phase A: raw scores fp32 -> SB bf16 ; stage Qs (FULL 64 shorts/row) ; stage Pt[0]
    for (int t = tid; t < 24*256; t += 512){
        int bh = t>>8, f4 = t&255;
        float4 x = *(const float4*)&WEI[((size_t)bh*S_ + j)*S_ + f4*4];
        short4 o; o.x=f2bf(x.x); o.y=f2bf(x.y); o.z=f2bf(x.z); o.w=f2bf(x.w);
        *(short4*)&SB[bh][f4*4] = o;
    }
    if (tid < 256){
        int row = tid>>3, q4 = tid&7;       // 32 rows x 8 uint4 = full 64 shorts
        uint4 v = {0,0,0,0};
        if (row < BH_) v = *(const uint4*)&QB[((size_t)row*S_ + j)*DH_ + q4*8];
        *(uint4*)&Qs[row][q4*8] = v;
    }
    #pragma unroll
    for (int u=0; u<2; ++u){
        int t = tid + u*512;
        int kl = t>>4, f4 = t&15;
        float4 x = *(const float4*)&pos[((size_t)kl*S_ + j)*DH_ + f4*4];
        short4 o; o.x=f2bf(x.x); o.y=f2bf(x.y); o.z=f2bf(x.z); o.w=f2bf(x.w);
        *(short4*)&Pt[0][kl][f4*4] = o;
    }
    __syncthreads();

    // --- Phase B: SB[bh][k] += Q[bh,:]·pos[k,j,:]  (16 chunks of 64 k)
    for (int kc=0; kc<16; ++kc){
        const int cur = kc & 1;
        float4 nx0, nx1;
        if (kc < 15){
            int t0 = tid,      kl0 = t0>>4, f40 = t0&15;
            int t1 = tid+512,  kl1 = t1>>4, f41 = t1&15;
            nx0 = *(const float4*)&pos[((size_t)((kc+1)*64+kl0)*S_ + j)*DH_ + f40*4];
            nx1 = *(const float4*)&pos[((size_t)((kc+1)*64+kl1)*S_ + j)*DH_ + f41*4];
        }
        f32x4 acc = {0.f,0.f,0.f,0.f};
        #pragma unroll
        for (int ks=0; ks<2; ++ks){
            bf16x8 a = *(const bf16x8*)&Qs[mi*16 + r16][ks*32 + g*8];
            bf16x8 b = *(const bf16x8*)&Pt[cur][ni*16 + r16][ks*32 + g*8];
            acc = MFMA16(a, b, acc);
        }
        #pragma unroll
        for (int r=0; r<4; ++r){
            int bh = mi*16 + g*4 + r;
            if (bh < BH_){
                int col = kc*64 + ni*16 + r16;
                SB[bh][col] = f2bf(bf2f(SB[bh][col]) + acc[r]);
            }
        }
        __syncthreads();
        if (kc < 15){
            int t0 = tid,      kl0 = t0>>4, f40 = t0&15;
            int t1 = tid+512,  kl1 = t1>>4, f41 = t1&15;
            short4 o0; o0.x=f2bf(nx0.x); o0.y=f2bf(nx0.y); o0.z=f2bf(nx0.z); o0.w=f2bf(nx0.w);
            short4 o1; o1.x=f2bf(nx1.x); o1.y=f2bf(nx1.y); o1.z=f2bf(nx1.z); o1.w=f2bf(nx1.w);
            *(short4*)&Pt[cur^1][kl0][f40*4] = o0;
            *(short4*)&Pt[cur^1][kl1][f41*4] = o1;
            __syncthreads();
        }
    }
    __syncthreads();

    // --- Phase C: softmax rows (wave w owns bh = w, w+8, w+16)
    #pragma unroll
    for (int rr=0; rr<3; ++rr){
        int bh = w + rr*8;
        const float* mrow = mask + (size_t)(bh/H_)*S_;
        float x[16];
        #pragma unroll
        for (int i=0;i<16;++i)
            x[i] = bf2f(SB[bh][i*64 + lane])*0.125f + mrow[i*64+lane]*(-1e9f);
        float mx = x[0];
        #pragma unroll
        for (int i=1;i<16;++i) mx = fmaxf(mx, x[i]);
        #pragma unroll
        for (int off=32; off>0; off>>=1) mx = fmaxf(mx, __shfl_xor(mx, off, 64));
        float sm = 0.f;
        #pragma unroll
        for (int i=0;i<16;++i){ x[i] = __expf(x[i]-mx); sm += x[i]; }
        #pragma unroll
        for (int off=32; off>0; off>>=1) sm += __shfl_xor(sm, off, 64);
        float inv = 1.0f / sm;
        float* wrow = &WEI[((size_t)bh*S_ + j)*S_];
        #pragma unroll
        for (int i=0;i<16;++i){
            float wt = x[i]*inv;
            wrow[i*64+lane] = wt;
            SB[bh][i*64+lane] = f2bf(wt);
        }
    }
    __syncthreads();

    // --- Phase D: PBIAS[bh][d] = sum_k W[bh][k]·pos[j][k][d]
    #pragma unroll
    for (int u=0; u<2; ++u){
        int t = tid + u*512;
        int kl = t>>4, d4 = t&15;
        float4 x = *(const float4*)&pos[((size_t)j*S_ + kl)*DH_ + d4*4];
        Pt[0][d4*4+0][kl] = f2bf(x.x);
        Pt[0][d4*4+1][kl] = f2bf(x.y);
        Pt[0][d4*4+2][kl] = f2bf(x.z);
        Pt[0][d4*4+3][kl] = f2bf(x.w);
    }
    __syncthreads();
    const int arow_base = (mi==0) ? 0 : 8;   // overlapping m-tiles {0-15, 8-23}
    f32x4 dacc = {0.f,0.f,0.f,0.f};
    for (int kc=0; kc<16; ++kc){
        const int cur = kc & 1;
        float4 nx0, nx1;
        if (kc < 15){
            int t0 = tid,      kl0 = t0>>4, d40 = t0&15;
            int t1 = tid+512,  kl1 = t1>>4, d41 = t1&15;
            nx0 = *(const float4*)&pos[((size_t)j*S_ + (kc+1)*64 + kl0)*DH_ + d40*4];
            nx1 = *(const float4*)&pos[((size_t)j*S_ + (kc+1)*64 + kl1)*DH_ + d41*4];
        }
        #pragma unroll
        for (int ks=0; ks<2; ++ks){
            bf16x8 a = *(const bf16x8*)&SB[arow_base + r16][kc*64 + ks*32 + g*8];
            bf16x8 b = *(const bf16x8*)&Pt[cur][ni*16 + r16][ks*32 + g*8];
            dacc = MFMA16(a, b, dacc);
        }
        __syncthreads();
        if (kc < 15){
            int t0 = tid,      kl0 = t0>>4, d40 = t0&15;
            int t1 = tid+512,  kl1 = t1>>4, d41 = t1&15;
            Pt[cur^1][d40*4+0][kl0] = f2bf(nx0.x);
            Pt[cur^1][d40*4+1][kl0] = f2bf(nx0.y);
            Pt[cur^1][d40*4+2][kl0] = f2bf(nx0.z);
            Pt[cur^1][d40*4+3][kl0] = f2bf(nx0.w);
            Pt[cur^1][d41*4+0][kl1] = f2bf(nx1.x);
            Pt[cur^1][d41*4+1][kl1] = f2bf(nx1.y);
            Pt[cur^1][d41*4+2][kl1] = f2bf(nx1.z);
            Pt[cur^1][d41*4+3][kl1] = f2bf(nx1.w);
            __syncthreads();
        }
    }
    #pragma unroll
    for (int r=0; r<4; ++r){
        int bh = arow_base + g*4 + r;
        bool keep = (mi==0) ? (bh < 16) : (bh >= 16);
        if (keep){
            int d = ni*16 + r16;
            size_t o = ((size_t)(bh/H_)*S_ + j)*D_ + (bh%H_)*DH_ + d;
            PBIAS[o] = f2bf(dacc[r]);
        }
    }
}

// ---------- K4: ctx = W @ V per bh via MFMA, + PBIAS -> CTXB bf16 ----------
__global__ __launch_bounds__(256) void wv_mfma_kernel(
    const float* __restrict__ sc, const short* __restrict__ VTB,
    const short* __restrict__ PBIAS, short* __restrict__ CTXB)
{
    const int bh = blockIdx.y, m0 = blockIdx.x*64;
    const float* W  = sc  + (size_t)bh*S_*S_;
    const short* VT = VTB + (size_t)bh*DH_*S_;
    __shared__ short Ws[64][72];
    __shared__ short Vs[64][72];
    const int tid = threadIdx.x;
    const int w = tid>>6, lane = tid&63, g = lane>>4, r16 = lane&15;
    f32x4 acc[4] = {};
    for (int kc=0; kc<16; ++kc){
        if (tid < 128){
            int row = tid>>1, half = tid&1;
            const float* src = &W[(size_t)(m0+row)*S_ + kc*64 + half*32];
            uint4* dst = (uint4*)&Ws[row][half*32];
            #pragma unroll
            for (int i=0;i<4;i++){
                float4 x0 = *(const float4*)&src[i*8];
                float4 x1 = *(const float4*)&src[i*8+4];
                dst[i] = pack8(x0,x1);
            }
        } else {
            int t2 = tid-128;
            int row = t2>>1, half = t2&1;
            const uint4* src = (const uint4*)&VT[(size_t)row*S_ + kc*64 + half*32];
            uint4* dst = (uint4*)&Vs[row][half*32];
            dst[0]=src[0]; dst[1]=src[1]; dst[2]=src[2]; dst[3]=src[3];
        }
        __syncthreads();
        #pragma unroll
        for (int ks=0; ks<2; ++ks){
            bf16x8 a = *(const bf16x8*)&Ws[w*16 + r16][ks*32 + g*8];
            #pragma unroll
            for (int ni=0; ni<4; ++ni){
                bf16x8 b = *(const bf16x8*)&Vs[ni*16 + r16][ks*32 + g*8];
                acc[ni] = MFMA16(a, b, acc[ni]);
            }
        }
        __syncthreads();
    }
    const int b = bh/H_, h = bh%H_;
    #pragma unroll
    for (int ni=0; ni<4; ++ni)
    #pragma unroll
    for (int r=0; r<4; ++r){
        int jj = m0 + w*16 + g*4 + r;
        int d = ni*16 + r16;
        size_t o = ((size_t)b*S_ + jj)*D_ + h*DH_ + d;
        CTXB[o] = f2bf(acc[ni][r] + bf2f(PBIAS[o]));
    }
}

// ---------- K5: out = ctxb @ Wo + bo (MFMA) ----------
__global__ __launch_bounds__(256) void out_mfma_kernel(
    const short* __restrict__ CTXB, const short* __restrict__ To,
    const float* __restrict__ bo, float* __restrict__ outp)
{
    const int m0 = blockIdx.y*64, n0 = blockIdx.x*64;
    __shared__ short As[64][72];
    __shared__ short Bs[64][72];
    const int tid = threadIdx.x;
    const int w = tid>>6, lane = tid&63, g = lane>>4, r16 = lane&15;
    f32x4 acc[4] = {};
    for (int kc=0; kc<12; ++kc){
        if (tid < 128){
            int row = tid>>1, half = tid&1;
            const uint4* src = (const uint4*)&CTXB[(size_t)(m0+row)*D_ + kc*64 + half*32];
            uint4* dst = (uint4*)&As[row][half*32];
            dst[0]=src[0]; dst[1]=src[1]; dst[2]=src[2]; dst[3]=src[3];
        } else {
            int t2 = tid-128;
            int row = t2>>1, half = t2&1;
            const uint4* src = (const uint4*)&To[(size_t)(n0+row)*D_ + kc*64 + half*32];
            uint4* dst = (uint4*)&Bs[row][half*32];
            dst[0]=src[0]; dst[1]=src[1]; dst[2]=src[2]; dst[3]=src[3];
        }
        __syncthreads();
        #pragma unroll
        for (int ks=0; ks<2; ++ks){
            bf16x8 a = *(const bf16x8*)&As[w*16 + r16][ks*32 + g*8];
            #pragma unroll
            for (int ni=0; ni<4; ++ni){
                bf16x8 b = *(const bf16x8*)&Bs[ni*16 + r16][ks*32 + g*8];
                acc[ni] = MFMA16(a, b, acc[ni]);
            }
        }
        __syncthreads();
    }
    #pragma unroll
    for (int ni=0; ni<4; ++ni)
    #pragma unroll
    for (int r=0; r<4; ++r){
        int m = m0 + w*16 + g*4 + r;
        int n = n0 + ni*16 + r16;
        outp[(size_t)m*D_ + n] = acc[ni][r] + bo[n];
    }
}

extern "C" void kernel_launch(void* const* d_in, const int* in_sizes, int n_in,
                              void* d_out, int out_size, void* d_ws, size_t ws_size,
                              hipStream_t stream) {
    const float* q_in = (const float*)d_in[0];
    const float* k_in = (const float*)d_in[1];
    const float* v_in = (const float*)d_in[2];
    const float* pos  = (const float*)d_in[3];
    const float* mask = (const float*)d_in[4];
    const float* Wq   = (const float*)d_in[5];
    const float* bq   = (const float*)d_in[6];
    const float* Wk   = (const float*)d_in[7];
    const float* bk   = (const float*)d_in[8];
    const float* Wv   = (const float*)d_in[9];
    const float* bv   = (const float*)d_in[10];
    const float* Wo   = (const float*)d_in[11];
    const float* bo   = (const float*)d_in[12];

    float* outp = (float*)d_out;               // (B,S,D)
    float* WEI  = outp + OUTSZ_;               // (B,H,S,S) raw scores -> weights (in place per j)

    char* w8 = (char*)d_ws;
    short* QB  = (short*)w8;                                   // 3,145,728 B
    short* KB  = (short*)(w8 + 1*3145728);
    short* VTB = (short*)(w8 + 2*3145728);
    short* WTq = (short*)(w8 + 3*3145728);                     // 4 x 1,179,648 B
    short* WTk = WTq + 768*768;
    short* WTv = WTk + 768*768;
    short* WTo = WTv + 768*768;
    char*  r2  = w8 + 3*3145728 + 4*1179648;                   // 14,155,776
    short* AQ  = (short*)r2;                                   // 3 x 3,145,728 B (pre-proj)
    short* AK  = AQ + (size_t)2048*768;
    short* AV  = AK + (size_t)2048*768;
    short* PBIAS = (short*)r2;                                 // alias (post-proj): 3,145,728 B
    short* CTXB  = PBIAS + (size_t)B_*S_*D_;                   // 3,145,728 B

    cvt_in_kernel   <<<dim3(1536,3),   256, 0, stream>>>(q_in,k_in,v_in,AQ,AK,AV);
    wt_kernel       <<<dim3(12,12,4),  256, 0, stream>>>(Wq,Wk,Wv,Wo,WTq,WTk,WTv,WTo);
    proj_mfma_kernel<<<dim3(12,16,3),  256, 0, stream>>>(AQ,AK,AV,WTq,WTk,WTv,bq,bk,bv,QB,KB,VTB);
    qk_mfma_kernel  <<<dim3(8,8,24),   256, 0, stream>>>(QB,KB,WEI);
    fused_j_kernel  <<<dim3(1024),     512, 0, stream>>>(pos,QB,mask,WEI,PBIAS);
    wv_mfma_kernel  <<<dim3(16,24),    256, 0, stream>>>(WEI,VTB,PBIAS,CTXB);
    out_mfma_kernel <<<dim3(12,32),    256, 0, stream>>>(CTXB,WTo,bo,outp);
}